// Round 18
// baseline (140.578 us; speedup 1.0000x reference)
//
#include <hip/hip_runtime.h>
#include <hip/hip_bf16.h>

typedef unsigned short u16;
typedef unsigned int   u32;
typedef __attribute__((ext_vector_type(8))) short bf16x8;
typedef __attribute__((ext_vector_type(4))) float f32x4;

#define NB   64
#define NTX  2048
#define ND   256
#define NL   1024

#if __has_builtin(__builtin_amdgcn_exp2f)
#define EXP2F(x) __builtin_amdgcn_exp2f(x)
#else
#define EXP2F(x) exp2f(x)
#endif

// Native reciprocal — guaranteed v_rcp_f32.
__device__ __forceinline__ float rcp_fast(float x){
  float r;
  asm volatile("v_rcp_f32 %0, %1" : "=v"(r) : "v"(x));
  return r;
}

__device__ __forceinline__ u16 f2bf(float f){
  union { float f; u32 u; } c; c.f = f;
  return (u16)((c.u + 0x7fffu + ((c.u >> 16) & 1u)) >> 16);
}
__device__ __forceinline__ u32 pk2(float a, float b){
  return (u32)f2bf(a) | ((u32)f2bf(b) << 16);
}
__device__ __forceinline__ float sigmf(float x){ return 1.f/(1.f+__expf(-x)); }
__device__ __forceinline__ float tanhf_fast(float x){
  x = fminf(fmaxf(x, -15.f), 15.f);
  float e = __expf(2.f*x);
  return (e - 1.f) / (e + 1.f);
}
// Padé [7/6] tanh, clamp [-4,4]: 1 v_rcp, no exp. err<=6.7e-4.
__device__ __forceinline__ float tanh_pade(float x){
  x = fminf(fmaxf(x, -4.f), 4.f);
  float t = x*x;
  float n = ((t + 378.f)*t + 17325.f)*t + 135135.f;
  float d = ((28.f*t + 3150.f)*t + 62370.f)*t + 135135.f;
  return x * n * rcp_fast(d);
}
__device__ __forceinline__ float dot_rowf(const float* __restrict__ row,
                                          const float* __restrict__ x, int K4){
  float acc = 0.f;
  for (int j = 0; j < K4; ++j){
    float4 w = *(const float4*)(row + j*4);
    const float* xp = x + j*4;
    acc += w.x*xp[0] + w.y*xp[1] + w.z*xp[2] + w.w*xp[3];
  }
  return acc;
}

// ---------------------------------------------------------------------------
// F1: blocks 0..15  : transposes [64][256] -> [256][64]
//     blocks 16..79 : fc1 batch-on-lanes -> p1T [256][64]
//     blocks 80..143: h_r1/h_r2 fp32 -> bf16 copies
// ---------------------------------------------------------------------------
__global__ __launch_bounds__(256) void k_pre1(
    const float* __restrict__ cv_text, const float* __restrict__ cv,
    const float* __restrict__ h_text,  const float* __restrict__ h_attn,
    const float* __restrict__ prenet_in,
    const float* __restrict__ fc1_w, const float* __restrict__ fc1_b,
    const float* __restrict__ h_r1, const float* __restrict__ h_r2,
    float* __restrict__ xtext, float* __restrict__ xattn,
    float* __restrict__ htT,  float* __restrict__ haT,
    float* __restrict__ p1T,
    u16* __restrict__ hb1, u16* __restrict__ hb2)
{
  __shared__ float ld[64][65];
  const int blk = blockIdx.x, tid = threadIdx.x;
  if (blk < 16){
    int a = blk >> 2; int c0 = (blk & 3)*64;
    const float* src = (a==0)?cv_text:(a==1)?cv:(a==2)?h_text:h_attn;
    float* dst = (a==0)?xtext:(a==1)?xattn:(a==2)?htT:haT;
    const int r = tid >> 2, q = tid & 3;
    #pragma unroll
    for (int i = 0; i < 4; ++i){
      float4 v = *(const float4*)(src + (size_t)r*256 + c0 + q*16 + i*4);
      ld[r][q*16+i*4+0] = v.x; ld[r][q*16+i*4+1] = v.y;
      ld[r][q*16+i*4+2] = v.z; ld[r][q*16+i*4+3] = v.w;
    }
    __syncthreads();
    const int cc = tid >> 2;
    #pragma unroll
    for (int i = 0; i < 4; ++i){
      int b0 = q*16 + i*4;
      float4 o = { ld[b0+0][cc], ld[b0+1][cc], ld[b0+2][cc], ld[b0+3][cc] };
      *(float4*)(dst + (size_t)(c0+cc)*64 + b0) = o;
    }
  } else if (blk < 80){
    const int wave = tid >> 6, lane = tid & 63;
    const int n = (blk - 16)*4 + wave;
    float acc = fc1_b[n];
    const float* wr = fc1_w + (size_t)n*80;
    const float* xr = prenet_in + (size_t)lane*80;
    #pragma unroll
    for (int k = 0; k < 80; k += 4){
      float4 w = *(const float4*)(wr + k);
      acc += w.x*xr[k] + w.y*xr[k+1] + w.z*xr[k+2] + w.w*xr[k+3];
    }
    p1T[n*64 + lane] = fmaxf(acc, 0.f);
  } else {
    const int t2 = blk - 80;
    const float* src = (t2 < 32) ? h_r1 : h_r2;
    u16* dst = (t2 < 32) ? hb1 : hb2;
    const int base = (t2 & 31)*2048 + tid*8;
    float4 a = *(const float4*)(src + base);
    float4 b = *(const float4*)(src + base + 4);
    uint4 o = { pk2(a.x,a.y), pk2(a.z,a.w), pk2(b.x,b.y), pk2(b.z,b.w) };
    *(uint4*)(dst + base) = o;
  }
}

// F2: fc2, 128 blocks (block = n), 4-wave k-split + LDS reduce.
__global__ __launch_bounds__(256) void k_pre2(
    const float* __restrict__ p1T,
    const float* __restrict__ fc2_w, const float* __restrict__ fc2_b,
    float* __restrict__ xtext, float* __restrict__ xattn)
{
  const int tid = threadIdx.x, w = tid >> 6, lane = tid & 63;
  const int n = blockIdx.x;
  __shared__ float red[4][64];
  float acc = 0.f;
  const float* wr = fc2_w + (size_t)n*256 + w*64;
  const float* xb = p1T + w*64*64 + lane;
  #pragma unroll
  for (int k = 0; k < 64; k += 4){
    float4 wv = *(const float4*)(wr + k);
    acc += wv.x*xb[(k+0)*64] + wv.y*xb[(k+1)*64]
         + wv.z*xb[(k+2)*64] + wv.w*xb[(k+3)*64];
  }
  red[w][lane] = acc;
  __syncthreads();
  if (w == 0){
    float v = fmaxf(red[0][lane]+red[1][lane]+red[2][lane]+red[3][lane] + fc2_b[n], 0.f);
    xtext[(size_t)(256+n)*64 + lane] = v;
    xattn[(size_t)(256+n)*64 + lane] = v;
  }
}

// F3: GRUs. 512 blocks x 512 threads (8 waves k-split + LDS reduce).
__global__ __launch_bounds__(512) void k_gru(
    const float* __restrict__ t_wih, const float* __restrict__ t_whh,
    const float* __restrict__ t_bih, const float* __restrict__ t_bhh,
    const float* __restrict__ a_wih, const float* __restrict__ a_whh,
    const float* __restrict__ a_bih, const float* __restrict__ a_bhh,
    const float* __restrict__ xtext, const float* __restrict__ xattn,
    const float* __restrict__ htT,  const float* __restrict__ haT,
    float* __restrict__ htnT, u16* __restrict__ xrib)
{
  const int tid = threadIdx.x, w = tid >> 6, lane = tid & 63;
  const int isA = blockIdx.x >= 256;
  const int d = blockIdx.x & 255;
  const float* wih = isA ? a_wih : t_wih;
  const float* whh = isA ? a_whh : t_whh;
  const float* xT  = isA ? xattn : xtext;
  const float* hT  = isA ? haT   : htT;
  __shared__ float red[8][6][64];
  float s0=0.f,s1=0.f,s2=0.f,s3=0.f,s4=0.f,s5=0.f;
  {
    const float* wr = wih + (size_t)d*384       + w*48;
    const float* wz = wih + (size_t)(256+d)*384 + w*48;
    const float* wn = wih + (size_t)(512+d)*384 + w*48;
    const float* xb = xT + w*48*64 + lane;
    #pragma unroll 4
    for (int k = 0; k < 48; k += 4){
      float4 ar = *(const float4*)(wr + k);
      float4 az = *(const float4*)(wz + k);
      float4 an = *(const float4*)(wn + k);
      float x0 = xb[(k+0)*64], x1 = xb[(k+1)*64];
      float x2 = xb[(k+2)*64], x3 = xb[(k+3)*64];
      s0 += ar.x*x0 + ar.y*x1 + ar.z*x2 + ar.w*x3;
      s1 += az.x*x0 + az.y*x1 + az.z*x2 + az.w*x3;
      s2 += an.x*x0 + an.y*x1 + an.z*x2 + an.w*x3;
    }
  }
  {
    const float* vr = whh + (size_t)d*256       + w*32;
    const float* vz = whh + (size_t)(256+d)*256 + w*32;
    const float* vn = whh + (size_t)(512+d)*256 + w*32;
    const float* hb = hT + w*32*64 + lane;
    #pragma unroll 4
    for (int k = 0; k < 32; k += 4){
      float4 ar = *(const float4*)(vr + k);
      float4 az = *(const float4*)(vz + k);
      float4 an = *(const float4*)(vn + k);
      float h0 = hb[(k+0)*64], h1 = hb[(k+1)*64];
      float h2 = hb[(k+2)*64], h3 = hb[(k+3)*64];
      s3 += ar.x*h0 + ar.y*h1 + ar.z*h2 + ar.w*h3;
      s4 += az.x*h0 + az.y*h1 + az.z*h2 + az.w*h3;
      s5 += an.x*h0 + an.y*h1 + an.z*h2 + an.w*h3;
    }
  }
  red[w][0][lane]=s0; red[w][1][lane]=s1; red[w][2][lane]=s2;
  red[w][3][lane]=s3; red[w][4][lane]=s4; red[w][5][lane]=s5;
  __syncthreads();
  if (w == 0){
    const float* bih = isA ? a_bih : t_bih;
    const float* bhh = isA ? a_bhh : t_bhh;
    float g6[6];
    #pragma unroll
    for (int i = 0; i < 6; ++i){
      float a = 0.f;
      #pragma unroll
      for (int ww = 0; ww < 8; ++ww) a += red[ww][i][lane];
      g6[i] = a;
    }
    float gir = bih[d]     + g6[0];
    float giz = bih[256+d] + g6[1];
    float gin = bih[512+d] + g6[2];
    float ghr = bhh[d]     + g6[3];
    float ghz = bhh[256+d] + g6[4];
    float ghn = bhh[512+d] + g6[5];
    float hd = hT[d*64 + lane];
    float r  = sigmf(gir + ghr), z = sigmf(giz + ghz);
    float nn = tanhf_fast(gin + r*ghn);
    float hnew = (1.f - z)*nn + z*hd;
    if (isA) xrib[(size_t)lane*512 + 256 + d] = f2bf(hnew);
    else     htnT[(size_t)d*64 + lane]        = hnew;
  }
}

// F4: qp. 256 blocks (block = d), 4-wave k-split + reduce.
__global__ __launch_bounds__(256) void k_qp(
    const float* __restrict__ tWm, const float* __restrict__ htnT,
    float* __restrict__ qp)
{
  const int tid = threadIdx.x, w = tid >> 6, lane = tid & 63;
  const int d = blockIdx.x;
  __shared__ float red[4][64];
  float acc = 0.f;
  const float* wr = tWm + (size_t)d*256 + w*64;
  const float* xb = htnT + w*64*64 + lane;
  #pragma unroll
  for (int k = 0; k < 64; k += 4){
    float4 wv = *(const float4*)(wr + k);
    acc += wv.x*xb[(k+0)*64] + wv.y*xb[(k+1)*64]
         + wv.z*xb[(k+2)*64] + wv.w*xb[(k+3)*64];
  }
  red[w][lane] = acc;
  __syncthreads();
  if (w == 0)
    qp[lane*ND + d] = red[0][lane]+red[1][lane]+red[2][lane]+red[3][lane];
}

// ---------------------------------------------------------------------------
// K2: attention — BARRIER-FREE waves. Grid (64 b, 16 ch of 128 rows), 256 thr.
// Each wave independently: 32 rows as 4x8-row register batches, software
// pipelined (two 8-row buffers); row-sum via 6-step shfl butterfly (in-wave);
// per-wave partial written straight to attnP. No LDS, no __syncthreads.
// ---------------------------------------------------------------------------
#define ATTN_PROC(E) \
  { \
    _Pragma("unroll") \
    for (int i = 0; i < 8; ++i){ \
      float t0 = tanh_pade(E[i].x + qv.x); \
      float t1 = tanh_pade(E[i].y + qv.y); \
      float t2 = tanh_pade(E[i].z + qv.z); \
      float t3 = tanh_pade(E[i].w + qv.w); \
      float s = vv.x*t0 + vv.y*t1 + vv.z*t2 + vv.w*t3; \
      s += __shfl_xor(s, 1);  s += __shfl_xor(s, 2); \
      s += __shfl_xor(s, 4);  s += __shfl_xor(s, 8); \
      s += __shfl_xor(s, 16); s += __shfl_xor(s, 32); \
      float wv_ = EXP2F(s * L2E); \
      sacc += wv_; \
      cx0 = __builtin_fmaf(wv_, E[i].x, cx0); \
      cx1 = __builtin_fmaf(wv_, E[i].y, cx1); \
      cx2 = __builtin_fmaf(wv_, E[i].z, cx2); \
      cx3 = __builtin_fmaf(wv_, E[i].w, cx3); \
    } \
  }

__global__ __launch_bounds__(256) void k_attn_part(
    const float* __restrict__ enc, const float* __restrict__ qp,
    const float* __restrict__ tv,  float* __restrict__ attnP)
{
  const int tid = threadIdx.x, b = blockIdx.x, ch = blockIdx.y;
  const int w = tid >> 6, lane = tid & 63;
  const float L2E = 1.4426950408f;
  const float4 qv = *(const float4*)(qp + b*ND + lane*4);
  const float4 vv = *(const float4*)(tv + lane*4);
  const float* base = enc + ((size_t)b*NTX + (size_t)ch*128 + w*32)*ND + lane*4;

  float cx0=0.f, cx1=0.f, cx2=0.f, cx3=0.f, sacc=0.f;
  float4 evA[8], evB[8];

  #pragma unroll
  for (int i = 0; i < 8; ++i) evA[i] = *(const float4*)(base + (size_t)i*ND);
  #pragma unroll
  for (int i = 0; i < 8; ++i) evB[i] = *(const float4*)(base + (size_t)(8+i)*ND);
  ATTN_PROC(evA)
  #pragma unroll
  for (int i = 0; i < 8; ++i) evA[i] = *(const float4*)(base + (size_t)(16+i)*ND);
  ATTN_PROC(evB)
  #pragma unroll
  for (int i = 0; i < 8; ++i) evB[i] = *(const float4*)(base + (size_t)(24+i)*ND);
  ATTN_PROC(evA)
  ATTN_PROC(evB)

  // per-wave partial: row index = b*64 + ch*4 + w
  float* dst = attnP + ((size_t)(b*64 + ch*4 + w))*257;
  float4 o = {cx0, cx1, cx2, cx3};
  *(float4*)(dst + lane*4) = o;
  if (lane == 0) dst[256] = sacc;
}

// K3: combine 64 wave-partials -> xrib rows 0..255 (bf16)
__global__ __launch_bounds__(256) void k_attn_red(
    const float* __restrict__ attnP, u16* __restrict__ xrib)
{
  const int tid = threadIdx.x, b = blockIdx.x;
  float c = 0.f, s = 0.f;
  for (int p = 0; p < 64; ++p){
    const float* src = attnP + ((size_t)(b*64 + p))*257;
    c += src[tid]; s += src[256];
  }
  xrib[(size_t)b*512 + tid] = f2bf(c / s);
}

// ---------------------------------------------------------------------------
// MFMA GEMMs (A direct from global bf16, no LDS staging).
// D[b][col]: b = fb*16+(lane>>4)*4+reg, col = lane&15.
// ---------------------------------------------------------------------------

// ri projection: 64 blocks x 512 threads; 8 waves k-split (64 each).
__global__ __launch_bounds__(512) void k_mm_ri(
    const u16* __restrict__ xrib, const float* __restrict__ ri_w,
    const float* __restrict__ ri_b, float* __restrict__ x0,
    u16* __restrict__ x0b)
{
  __shared__ float Rs[8][4][4][65];
  const int tid = threadIdx.x, lane = tid & 63, w = tid >> 6;
  const int n0 = blockIdx.x * 16;
  f32x4 acc[4];
  #pragma unroll
  for (int i = 0; i < 4; ++i) acc[i] = (f32x4){0.f,0.f,0.f,0.f};
  const int kbase = w*64;
  const float* wr = ri_w + (size_t)(n0 + (lane & 15))*512 + kbase + (lane >> 4)*8;
  const u16* xs = xrib + (size_t)(lane & 15)*512 + kbase + (lane >> 4)*8;
  #pragma unroll
  for (int t = 0; t < 2; ++t){
    float4 wa = *(const float4*)(wr + t*32);
    float4 wb = *(const float4*)(wr + t*32 + 4);
    union { bf16x8 v; uint4 u; } bf;
    bf.u.x = pk2(wa.x,wa.y); bf.u.y = pk2(wa.z,wa.w);
    bf.u.z = pk2(wb.x,wb.y); bf.u.w = pk2(wb.z,wb.w);
    #pragma unroll
    for (int fb = 0; fb < 4; ++fb){
      union { bf16x8 v; uint4 u; } af;
      af.u = *(const uint4*)(xs + fb*16*512 + t*32);
      acc[fb] = __builtin_amdgcn_mfma_f32_16x16x32_bf16(af.v, bf.v, acc[fb], 0, 0, 0);
    }
  }
  #pragma unroll
  for (int fb = 0; fb < 4; ++fb)
    #pragma unroll
    for (int r = 0; r < 4; ++r) Rs[w][fb][r][lane] = acc[fb][r];
  __syncthreads();
  if (tid < 256){
    const int b = tid >> 2, c4 = (tid & 3)*4;
    const int fb = b >> 4, q = (b >> 2) & 3, reg = b & 3;
    #pragma unroll
    for (int cc = 0; cc < 4; ++cc){
      const int c = c4 + cc;
      float v = ri_b[n0 + c];
      #pragma unroll
      for (int ww = 0; ww < 8; ++ww) v += Rs[ww][fb][reg][q*16 + c];
      x0[(size_t)b*1024 + n0 + c]  = v;
      x0b[(size_t)b*1024 + n0 + c] = f2bf(v);
    }
  }
}

// ---------------------------------------------------------------------------
// Fused LSTM layer: 256 blocks x 1024 threads (16 waves). Block = 4 j-cols;
// 16 MFMA rows = 4 gates x 4 j. Waves 0..7: ih K-chunks of 128; 8..15: hh.
// LDS reduce, then same block applies cell + residual.
// ---------------------------------------------------------------------------
__global__ __launch_bounds__(1024) void k_lstm(
    const float* __restrict__ Wih, const float* __restrict__ Whh,
    const u16* __restrict__ xb, const u16* __restrict__ hb,
    const float* __restrict__ bih, const float* __restrict__ bhh,
    const float* __restrict__ c_in,
    const float* __restrict__ xin, float* __restrict__ xout,
    u16* __restrict__ xoutb)
{
  __shared__ float Rs[16][4][4][65];
  const int tid = threadIdx.x, lane = tid & 63, w = tid >> 6;
  const int j0 = blockIdx.x * 4;
  const float* W = (w < 8) ? Wih : Whh;
  const u16*   X = (w < 8) ? xb  : hb;
  const int kbase = (w & 7) * 128;

  f32x4 acc[4];
  #pragma unroll
  for (int i = 0; i < 4; ++i) acc[i] = (f32x4){0.f,0.f,0.f,0.f};
  const int r16 = lane & 15;
  const int g = r16 >> 2, jq = r16 & 3;
  const float* wr = W + (size_t)(g*1024 + j0 + jq)*1024 + kbase + (lane >> 4)*8;
  #pragma unroll
  for (int t = 0; t < 4; ++t){
    float4 wa = *(const float4*)(wr + t*32);
    float4 wb = *(const float4*)(wr + t*32 + 4);
    union { bf16x8 v; uint4 u; } bf;
    bf.u.x = pk2(wa.x,wa.y); bf.u.y = pk2(wa.z,wa.w);
    bf.u.z = pk2(wb.x,wb.y); bf.u.w = pk2(wb.z,wb.w);
    #pragma unroll
    for (int fb = 0; fb < 4; ++fb){
      union { bf16x8 v; uint4 u; } af;
      af.u = *(const uint4*)(X + (size_t)(fb*16 + r16)*1024 + kbase + (lane >> 4)*8 + t*32);
      acc[fb] = __builtin_amdgcn_mfma_f32_16x16x32_bf16(af.v, bf.v, acc[fb], 0, 0, 0);
    }
  }
  #pragma unroll
  for (int fb = 0; fb < 4; ++fb)
    #pragma unroll
    for (int r = 0; r < 4; ++r) Rs[w][fb][r][lane] = acc[fb][r];
  __syncthreads();

  if (tid < 256){
    const int b  = tid >> 2, jq2 = tid & 3;
    const int j  = j0 + jq2;
    const int fb = b >> 4, q = (b >> 2) & 3, reg = b & 3;
    float gate[4];
    #pragma unroll
    for (int gg = 0; gg < 4; ++gg){
      const int li = q*16 + gg*4 + jq2;
      float a = bih[gg*1024 + j] + bhh[gg*1024 + j];
      #pragma unroll
      for (int ww = 0; ww < 16; ++ww) a += Rs[ww][fb][reg][li];
      gate[gg] = a;
    }
    float ii = sigmf(gate[0]), ff = sigmf(gate[1]);
    float gv = tanhf_fast(gate[2]), oo = sigmf(gate[3]);
    float cc = ff * c_in[(size_t)b*1024 + j] + ii * gv;
    float hh = oo * tanhf_fast(cc);
    float xo = xin[(size_t)b*1024 + j] + hh;
    xout[(size_t)b*1024 + j]  = xo;
    xoutb[(size_t)b*1024 + j] = f2bf(xo);
  }
}

// K7: mel projection — only rows with col%20 < 2 of mp_w are needed.
__global__ __launch_bounds__(256) void k_mels(
    const float* __restrict__ x2, const float* __restrict__ mp_w,
    float* __restrict__ out)
{
  const int tid = threadIdx.x, b = blockIdx.x;
  __shared__ float xL[NL];
  #pragma unroll
  for (int i = 0; i < 4; ++i){
    int j = tid + 256*i;
    xL[j] = x2[(size_t)b*NL + j];
  }
  __syncthreads();
  if (tid < 160){
    int m = tid >> 1, r = tid & 1;
    float acc = dot_rowf(mp_w + (size_t)(m*20 + r)*NL, xL, 256);
    out[b*160 + tid] = acc;
  }
}

// ---------------------------------------------------------------------------
extern "C" void kernel_launch(void* const* d_in, const int* in_sizes, int n_in,
                              void* d_out, int out_size, void* d_ws, size_t ws_size,
                              hipStream_t stream)
{
  (void)in_sizes; (void)n_in; (void)out_size; (void)ws_size;
  const float* enc     = (const float*)d_in[0];
  const float* pre_in  = (const float*)d_in[2];
  const float* h_text  = (const float*)d_in[3];
  const float* h_attn  = (const float*)d_in[5];
  const float* h_r1    = (const float*)d_in[6];
  const float* h_r2    = (const float*)d_in[7];
  const float* c_r1    = (const float*)d_in[8];
  const float* c_r2    = (const float*)d_in[9];
  const float* cv_text = (const float*)d_in[10];
  const float* cv      = (const float*)d_in[12];
  const float* fc1_w   = (const float*)d_in[13];
  const float* fc1_b   = (const float*)d_in[14];
  const float* fc2_w   = (const float*)d_in[15];
  const float* fc2_b   = (const float*)d_in[16];
  const float* tWm     = (const float*)d_in[17];
  const float* tv      = (const float*)d_in[18];
  const float* t_wih   = (const float*)d_in[21];
  const float* t_whh   = (const float*)d_in[22];
  const float* t_bih   = (const float*)d_in[23];
  const float* t_bhh   = (const float*)d_in[24];
  const float* a_wih   = (const float*)d_in[29];
  const float* a_whh   = (const float*)d_in[30];
  const float* a_bih   = (const float*)d_in[31];
  const float* a_bhh   = (const float*)d_in[32];
  const float* ri_w    = (const float*)d_in[33];
  const float* ri_b    = (const float*)d_in[34];
  const float* l1_wih  = (const float*)d_in[35];
  const float* l1_whh  = (const float*)d_in[36];
  const float* l1_bih  = (const float*)d_in[37];
  const float* l1_bhh  = (const float*)d_in[38];
  const float* l2_wih  = (const float*)d_in[39];
  const float* l2_whh  = (const float*)d_in[40];
  const float* l2_bih  = (const float*)d_in[41];
  const float* l2_bhh  = (const float*)d_in[42];
  const float* mp_w    = (const float*)d_in[43];

  // workspace layout (float units, 16B-aligned regions), ~9 MB
  float* ws    = (float*)d_ws;
  float* qp    = ws;                    // 16384
  float* attnP = qp    + 16384;         // 64*64*257 = 1052672
  float* x0    = attnP + 1052672;       // 65536
  float* x1    = x0    + 65536;
  float* x2    = x1    + 65536;
  float* xtext = x2    + 65536;         // 24576
  float* xattn = xtext + 24576;         // 24576
  float* htT   = xattn + 24576;         // 16384
  float* haT   = htT   + 16384;
  float* htnT  = haT   + 16384;
  float* p1T   = htnT  + 16384;         // 16384
  u16*   hb1   = (u16*)(p1T + 16384);   // 65536 u16
  u16*   hb2   = hb1 + 65536;
  u16*   xrib  = hb2 + 65536;           // 64*512
  u16*   x0b   = xrib + 32768;          // 64*1024
  u16*   x1b   = x0b + 65536;
  u16*   x2b   = x1b + 65536;           // written, unused

  k_pre1<<<144, 256, 0, stream>>>(cv_text, cv, h_text, h_attn,
      pre_in, fc1_w, fc1_b, h_r1, h_r2,
      xtext, xattn, htT, haT, p1T, hb1, hb2);
  k_pre2<<<128, 256, 0, stream>>>(p1T, fc2_w, fc2_b, xtext, xattn);
  k_gru<<<512, 512, 0, stream>>>(t_wih, t_whh, t_bih, t_bhh,
      a_wih, a_whh, a_bih, a_bhh, xtext, xattn, htT, haT, htnT, xrib);
  k_qp<<<256, 256, 0, stream>>>(tWm, htnT, qp);

  k_attn_part<<<dim3(64,16), 256, 0, stream>>>(enc, qp, tv, attnP);
  k_attn_red<<<64, 256, 0, stream>>>(attnP, xrib);

  k_mm_ri<<<64, 512, 0, stream>>>(xrib, ri_w, ri_b, x0, x0b);

  k_lstm<<<256, 1024, 0, stream>>>(l1_wih, l1_whh, x0b, hb1,
      l1_bih, l1_bhh, c_r1, x0, x1, x1b);
  k_lstm<<<256, 1024, 0, stream>>>(l2_wih, l2_whh, x1b, hb2,
      l2_bih, l2_bhh, c_r2, x1, x2, x2b);

  k_mels<<<64, 256, 0, stream>>>(x2, mp_w, (float*)d_out);
}

// Round 20
// 113.594 us; speedup vs baseline: 1.2376x; 1.2376x over previous
//
#include <hip/hip_runtime.h>
#include <hip/hip_bf16.h>

typedef unsigned short u16;
typedef unsigned int   u32;
typedef __attribute__((ext_vector_type(8))) short bf16x8;
typedef __attribute__((ext_vector_type(4))) float f32x4;
typedef __attribute__((ext_vector_type(4))) float f32x4v;

#define NB   64
#define NTX  2048
#define ND   256
#define NL   1024

#if __has_builtin(__builtin_amdgcn_exp2f)
#define EXP2F(x) __builtin_amdgcn_exp2f(x)
#else
#define EXP2F(x) exp2f(x)
#endif
#if __has_builtin(__builtin_amdgcn_rcpf)
#define RCPF(x) __builtin_amdgcn_rcpf(x)
#else
#define RCPF(x) (1.0f/(x))
#endif

__device__ __forceinline__ u16 f2bf(float f){
  union { float f; u32 u; } c; c.f = f;
  return (u16)((c.u + 0x7fffu + ((c.u >> 16) & 1u)) >> 16);
}
__device__ __forceinline__ u32 pk2(float a, float b){
  return (u32)f2bf(a) | ((u32)f2bf(b) << 16);
}
__device__ __forceinline__ float sigmf(float x){ return 1.f/(1.f+__expf(-x)); }
__device__ __forceinline__ float tanhf_fast(float x){
  x = fminf(fmaxf(x, -15.f), 15.f);
  float e = __expf(2.f*x);
  return (e - 1.f) / (e + 1.f);
}
__device__ __forceinline__ float dot_rowf(const float* __restrict__ row,
                                          const float* __restrict__ x, int K4){
  float acc = 0.f;
  for (int j = 0; j < K4; ++j){
    float4 w = *(const float4*)(row + j*4);
    const float* xp = x + j*4;
    acc += w.x*xp[0] + w.y*xp[1] + w.z*xp[2] + w.w*xp[3];
  }
  return acc;
}

// ---------------------------------------------------------------------------
// F1: blocks 0..15  : transposes [64][256] -> [256][64]
//     blocks 16..79 : fc1 batch-on-lanes -> p1T [256][64]
//     blocks 80..143: h_r1/h_r2 fp32 -> bf16 copies
// ---------------------------------------------------------------------------
__global__ __launch_bounds__(256) void k_pre1(
    const float* __restrict__ cv_text, const float* __restrict__ cv,
    const float* __restrict__ h_text,  const float* __restrict__ h_attn,
    const float* __restrict__ prenet_in,
    const float* __restrict__ fc1_w, const float* __restrict__ fc1_b,
    const float* __restrict__ h_r1, const float* __restrict__ h_r2,
    float* __restrict__ xtext, float* __restrict__ xattn,
    float* __restrict__ htT,  float* __restrict__ haT,
    float* __restrict__ p1T,
    u16* __restrict__ hb1, u16* __restrict__ hb2)
{
  __shared__ float ld[64][65];
  const int blk = blockIdx.x, tid = threadIdx.x;
  if (blk < 16){
    int a = blk >> 2; int c0 = (blk & 3)*64;
    const float* src = (a==0)?cv_text:(a==1)?cv:(a==2)?h_text:h_attn;
    float* dst = (a==0)?xtext:(a==1)?xattn:(a==2)?htT:haT;
    const int r = tid >> 2, q = tid & 3;
    #pragma unroll
    for (int i = 0; i < 4; ++i){
      float4 v = *(const float4*)(src + (size_t)r*256 + c0 + q*16 + i*4);
      ld[r][q*16+i*4+0] = v.x; ld[r][q*16+i*4+1] = v.y;
      ld[r][q*16+i*4+2] = v.z; ld[r][q*16+i*4+3] = v.w;
    }
    __syncthreads();
    const int cc = tid >> 2;
    #pragma unroll
    for (int i = 0; i < 4; ++i){
      int b0 = q*16 + i*4;
      float4 o = { ld[b0+0][cc], ld[b0+1][cc], ld[b0+2][cc], ld[b0+3][cc] };
      *(float4*)(dst + (size_t)(c0+cc)*64 + b0) = o;
    }
  } else if (blk < 80){
    const int wave = tid >> 6, lane = tid & 63;
    const int n = (blk - 16)*4 + wave;
    float acc = fc1_b[n];
    const float* wr = fc1_w + (size_t)n*80;
    const float* xr = prenet_in + (size_t)lane*80;
    #pragma unroll
    for (int k = 0; k < 80; k += 4){
      float4 w = *(const float4*)(wr + k);
      acc += w.x*xr[k] + w.y*xr[k+1] + w.z*xr[k+2] + w.w*xr[k+3];
    }
    p1T[n*64 + lane] = fmaxf(acc, 0.f);
  } else {
    const int t2 = blk - 80;
    const float* src = (t2 < 32) ? h_r1 : h_r2;
    u16* dst = (t2 < 32) ? hb1 : hb2;
    const int base = (t2 & 31)*2048 + tid*8;
    float4 a = *(const float4*)(src + base);
    float4 b = *(const float4*)(src + base + 4);
    uint4 o = { pk2(a.x,a.y), pk2(a.z,a.w), pk2(b.x,b.y), pk2(b.z,b.w) };
    *(uint4*)(dst + base) = o;
  }
}

// F2: fc2, 128 blocks (block = n), 4-wave k-split + LDS reduce.
__global__ __launch_bounds__(256) void k_pre2(
    const float* __restrict__ p1T,
    const float* __restrict__ fc2_w, const float* __restrict__ fc2_b,
    float* __restrict__ xtext, float* __restrict__ xattn)
{
  const int tid = threadIdx.x, w = tid >> 6, lane = tid & 63;
  const int n = blockIdx.x;
  __shared__ float red[4][64];
  float acc = 0.f;
  const float* wr = fc2_w + (size_t)n*256 + w*64;
  const float* xb = p1T + w*64*64 + lane;
  #pragma unroll
  for (int k = 0; k < 64; k += 4){
    float4 wv = *(const float4*)(wr + k);
    acc += wv.x*xb[(k+0)*64] + wv.y*xb[(k+1)*64]
         + wv.z*xb[(k+2)*64] + wv.w*xb[(k+3)*64];
  }
  red[w][lane] = acc;
  __syncthreads();
  if (w == 0){
    float v = fmaxf(red[0][lane]+red[1][lane]+red[2][lane]+red[3][lane] + fc2_b[n], 0.f);
    xtext[(size_t)(256+n)*64 + lane] = v;
    xattn[(size_t)(256+n)*64 + lane] = v;
  }
}

// F3: GRUs. 512 blocks x 512 threads (8 waves k-split + LDS reduce).
__global__ __launch_bounds__(512) void k_gru(
    const float* __restrict__ t_wih, const float* __restrict__ t_whh,
    const float* __restrict__ t_bih, const float* __restrict__ t_bhh,
    const float* __restrict__ a_wih, const float* __restrict__ a_whh,
    const float* __restrict__ a_bih, const float* __restrict__ a_bhh,
    const float* __restrict__ xtext, const float* __restrict__ xattn,
    const float* __restrict__ htT,  const float* __restrict__ haT,
    float* __restrict__ htnT, u16* __restrict__ xrib)
{
  const int tid = threadIdx.x, w = tid >> 6, lane = tid & 63;
  const int isA = blockIdx.x >= 256;
  const int d = blockIdx.x & 255;
  const float* wih = isA ? a_wih : t_wih;
  const float* whh = isA ? a_whh : t_whh;
  const float* xT  = isA ? xattn : xtext;
  const float* hT  = isA ? haT   : htT;
  __shared__ float red[8][6][64];
  float s0=0.f,s1=0.f,s2=0.f,s3=0.f,s4=0.f,s5=0.f;
  {
    const float* wr = wih + (size_t)d*384       + w*48;
    const float* wz = wih + (size_t)(256+d)*384 + w*48;
    const float* wn = wih + (size_t)(512+d)*384 + w*48;
    const float* xb = xT + w*48*64 + lane;
    #pragma unroll 4
    for (int k = 0; k < 48; k += 4){
      float4 ar = *(const float4*)(wr + k);
      float4 az = *(const float4*)(wz + k);
      float4 an = *(const float4*)(wn + k);
      float x0 = xb[(k+0)*64], x1 = xb[(k+1)*64];
      float x2 = xb[(k+2)*64], x3 = xb[(k+3)*64];
      s0 += ar.x*x0 + ar.y*x1 + ar.z*x2 + ar.w*x3;
      s1 += az.x*x0 + az.y*x1 + az.z*x2 + az.w*x3;
      s2 += an.x*x0 + an.y*x1 + an.z*x2 + an.w*x3;
    }
  }
  {
    const float* vr = whh + (size_t)d*256       + w*32;
    const float* vz = whh + (size_t)(256+d)*256 + w*32;
    const float* vn = whh + (size_t)(512+d)*256 + w*32;
    const float* hb = hT + w*32*64 + lane;
    #pragma unroll 4
    for (int k = 0; k < 32; k += 4){
      float4 ar = *(const float4*)(vr + k);
      float4 az = *(const float4*)(vz + k);
      float4 an = *(const float4*)(vn + k);
      float h0 = hb[(k+0)*64], h1 = hb[(k+1)*64];
      float h2 = hb[(k+2)*64], h3 = hb[(k+3)*64];
      s3 += ar.x*h0 + ar.y*h1 + ar.z*h2 + ar.w*h3;
      s4 += az.x*h0 + az.y*h1 + az.z*h2 + az.w*h3;
      s5 += an.x*h0 + an.y*h1 + an.z*h2 + an.w*h3;
    }
  }
  red[w][0][lane]=s0; red[w][1][lane]=s1; red[w][2][lane]=s2;
  red[w][3][lane]=s3; red[w][4][lane]=s4; red[w][5][lane]=s5;
  __syncthreads();
  if (w == 0){
    const float* bih = isA ? a_bih : t_bih;
    const float* bhh = isA ? a_bhh : t_bhh;
    float g6[6];
    #pragma unroll
    for (int i = 0; i < 6; ++i){
      float a = 0.f;
      #pragma unroll
      for (int ww = 0; ww < 8; ++ww) a += red[ww][i][lane];
      g6[i] = a;
    }
    float gir = bih[d]     + g6[0];
    float giz = bih[256+d] + g6[1];
    float gin = bih[512+d] + g6[2];
    float ghr = bhh[d]     + g6[3];
    float ghz = bhh[256+d] + g6[4];
    float ghn = bhh[512+d] + g6[5];
    float hd = hT[d*64 + lane];
    float r  = sigmf(gir + ghr), z = sigmf(giz + ghz);
    float nn = tanhf_fast(gin + r*ghn);
    float hnew = (1.f - z)*nn + z*hd;
    if (isA) xrib[(size_t)lane*512 + 256 + d] = f2bf(hnew);
    else     htnT[(size_t)d*64 + lane]        = hnew;
  }
}

// F4: qp. 256 blocks (block = d), 4-wave k-split + reduce.
__global__ __launch_bounds__(256) void k_qp(
    const float* __restrict__ tWm, const float* __restrict__ htnT,
    float* __restrict__ qp)
{
  const int tid = threadIdx.x, w = tid >> 6, lane = tid & 63;
  const int d = blockIdx.x;
  __shared__ float red[4][64];
  float acc = 0.f;
  const float* wr = tWm + (size_t)d*256 + w*64;
  const float* xb = htnT + w*64*64 + lane;
  #pragma unroll
  for (int k = 0; k < 64; k += 4){
    float4 wv = *(const float4*)(wr + k);
    acc += wv.x*xb[(k+0)*64] + wv.y*xb[(k+1)*64]
         + wv.z*xb[(k+2)*64] + wv.w*xb[(k+3)*64];
  }
  red[w][lane] = acc;
  __syncthreads();
  if (w == 0)
    qp[lane*ND + d] = red[0][lane]+red[1][lane]+red[2][lane]+red[3][lane];
}

// ---------------------------------------------------------------------------
// K2: attention partial pass, batch-load / flat-reduce form (R15 champion),
// enc reads via NONTEMPORAL loads (clang ext_vector type; read-once stream).
// Grid (64 b, 32 chunks of 64 t), 256 thr. Wave owns 16 rows.
// ---------------------------------------------------------------------------
__global__ __launch_bounds__(256) void k_attn_part(
    const float* __restrict__ enc, const float* __restrict__ qp,
    const float* __restrict__ tv,  float* __restrict__ attnP)
{
  const int tid = threadIdx.x, b = blockIdx.x, ch = blockIdx.y;
  const int w = tid >> 6, lane = tid & 63;
  const float C2  = 2.885390082f;      // 2*log2(e)
  const float L2E = 1.4426950408f;     // log2(e)
  __shared__ float qpL[256], vL[256];
  __shared__ float part[4][16][65];
  __shared__ float wbc[4][16];
  __shared__ float ctxL[4][256], sL[4];
  qpL[tid] = qp[b*ND + tid] * C2;
  vL[tid]  = tv[tid] * 2.f;
  __syncthreads();

  const float q0 = qpL[lane*4+0], q1 = qpL[lane*4+1], q2 = qpL[lane*4+2], q3 = qpL[lane*4+3];
  const float v0 = vL[lane*4+0],  v1 = vL[lane*4+1],  v2 = vL[lane*4+2],  v3 = vL[lane*4+3];
  float vs = 0.5f*(v0 + v1 + v2 + v3);
  #pragma unroll
  for (int off = 1; off < 64; off <<= 1) vs += __shfl_xor(vs, off);
  const float VS = vs;

  // S1: batch-load 16 rows (independent, nontemporal, ext_vector type)
  const float* base = enc + ((size_t)b*NTX + (size_t)ch*64 + w*16)*ND + lane*4;
  f32x4v ev[16];
  #pragma unroll
  for (int i = 0; i < 16; ++i)
    ev[i] = __builtin_nontemporal_load((const f32x4v*)(base + (size_t)i*ND));

  // S2: per-lane partial scores
  #pragma unroll
  for (int i = 0; i < 16; ++i){
    float u0 = EXP2F(__builtin_fmaf(ev[i][0], C2, q0));
    float u1 = EXP2F(__builtin_fmaf(ev[i][1], C2, q1));
    float u2 = EXP2F(__builtin_fmaf(ev[i][2], C2, q2));
    float u3 = EXP2F(__builtin_fmaf(ev[i][3], C2, q3));
    part[w][i][lane] = v0*RCPF(u0 + 1.f) + v1*RCPF(u1 + 1.f)
                     + v2*RCPF(u2 + 1.f) + v3*RCPF(u3 + 1.f);
  }
  __syncthreads();

  // S3: reduce each row: lane -> (row rr, quarter q4); 16 adds + 2 shfl
  {
    const int rr = lane >> 2, q4 = lane & 3;
    float s = 0.f;
    #pragma unroll
    for (int i = 0; i < 16; ++i) s += part[w][rr][q4*16 + i];
    s += __shfl_xor(s, 1);
    s += __shfl_xor(s, 2);
    if (q4 == 0) wbc[w][rr] = EXP2F((VS - s) * L2E);
  }
  __syncthreads();

  // S4: weighted context from in-register rows
  float cx0=0.f, cx1=0.f, cx2=0.f, cx3=0.f, sacc=0.f;
  #pragma unroll
  for (int r = 0; r < 16; ++r){
    float wv = wbc[w][r];
    sacc += wv;
    cx0 = __builtin_fmaf(wv, ev[r][0], cx0);
    cx1 = __builtin_fmaf(wv, ev[r][1], cx1);
    cx2 = __builtin_fmaf(wv, ev[r][2], cx2);
    cx3 = __builtin_fmaf(wv, ev[r][3], cx3);
  }
  ctxL[w][lane*4+0]=cx0; ctxL[w][lane*4+1]=cx1;
  ctxL[w][lane*4+2]=cx2; ctxL[w][lane*4+3]=cx3;
  if (lane == 0) sL[w] = sacc;
  __syncthreads();
  float c = ctxL[0][tid]+ctxL[1][tid]+ctxL[2][tid]+ctxL[3][tid];
  float* dst = attnP + ((size_t)b*32 + ch)*257;
  dst[tid] = c;
  if (tid == 0) dst[256] = sL[0]+sL[1]+sL[2]+sL[3];
}

// K3: combine 32 chunk partials -> xrib rows 0..255 (bf16)
__global__ __launch_bounds__(256) void k_attn_red(
    const float* __restrict__ attnP, u16* __restrict__ xrib)
{
  const int tid = threadIdx.x, b = blockIdx.x;
  float c = 0.f, s = 0.f;
  for (int ch = 0; ch < 32; ++ch){
    const float* src = attnP + ((size_t)b*32 + ch)*257;
    c += src[tid]; s += src[256];
  }
  xrib[(size_t)b*512 + tid] = f2bf(c / s);
}

// ---------------------------------------------------------------------------
// MFMA GEMMs (A direct from global bf16, no LDS staging).
// D[b][col]: b = fb*16+(lane>>4)*4+reg, col = lane&15.
// ---------------------------------------------------------------------------

// ri projection: 64 blocks x 512 threads; 8 waves k-split (64 each).
__global__ __launch_bounds__(512) void k_mm_ri(
    const u16* __restrict__ xrib, const float* __restrict__ ri_w,
    const float* __restrict__ ri_b, float* __restrict__ x0,
    u16* __restrict__ x0b)
{
  __shared__ float Rs[8][4][4][65];
  const int tid = threadIdx.x, lane = tid & 63, w = tid >> 6;
  const int n0 = blockIdx.x * 16;
  f32x4 acc[4];
  #pragma unroll
  for (int i = 0; i < 4; ++i) acc[i] = (f32x4){0.f,0.f,0.f,0.f};
  const int kbase = w*64;
  const float* wr = ri_w + (size_t)(n0 + (lane & 15))*512 + kbase + (lane >> 4)*8;
  const u16* xs = xrib + (size_t)(lane & 15)*512 + kbase + (lane >> 4)*8;
  #pragma unroll
  for (int t = 0; t < 2; ++t){
    float4 wa = *(const float4*)(wr + t*32);
    float4 wb = *(const float4*)(wr + t*32 + 4);
    union { bf16x8 v; uint4 u; } bf;
    bf.u.x = pk2(wa.x,wa.y); bf.u.y = pk2(wa.z,wa.w);
    bf.u.z = pk2(wb.x,wb.y); bf.u.w = pk2(wb.z,wb.w);
    #pragma unroll
    for (int fb = 0; fb < 4; ++fb){
      union { bf16x8 v; uint4 u; } af;
      af.u = *(const uint4*)(xs + fb*16*512 + t*32);
      acc[fb] = __builtin_amdgcn_mfma_f32_16x16x32_bf16(af.v, bf.v, acc[fb], 0, 0, 0);
    }
  }
  #pragma unroll
  for (int fb = 0; fb < 4; ++fb)
    #pragma unroll
    for (int r = 0; r < 4; ++r) Rs[w][fb][r][lane] = acc[fb][r];
  __syncthreads();
  if (tid < 256){
    const int b = tid >> 2, c4 = (tid & 3)*4;
    const int fb = b >> 4, q = (b >> 2) & 3, reg = b & 3;
    #pragma unroll
    for (int cc = 0; cc < 4; ++cc){
      const int c = c4 + cc;
      float v = ri_b[n0 + c];
      #pragma unroll
      for (int ww = 0; ww < 8; ++ww) v += Rs[ww][fb][reg][q*16 + c];
      x0[(size_t)b*1024 + n0 + c]  = v;
      x0b[(size_t)b*1024 + n0 + c] = f2bf(v);
    }
  }
}

// ---------------------------------------------------------------------------
// Fused LSTM layer: 256 blocks x 1024 threads (16 waves). Block = 4 j-cols;
// 16 MFMA rows = 4 gates x 4 j. Waves 0..7: ih K-chunks of 128; 8..15: hh.
// LDS reduce, then same block applies cell + residual.
// ---------------------------------------------------------------------------
__global__ __launch_bounds__(1024) void k_lstm(
    const float* __restrict__ Wih, const float* __restrict__ Whh,
    const u16* __restrict__ xb, const u16* __restrict__ hb,
    const float* __restrict__ bih, const float* __restrict__ bhh,
    const float* __restrict__ c_in,
    const float* __restrict__ xin, float* __restrict__ xout,
    u16* __restrict__ xoutb)
{
  __shared__ float Rs[16][4][4][65];
  const int tid = threadIdx.x, lane = tid & 63, w = tid >> 6;
  const int j0 = blockIdx.x * 4;
  const float* W = (w < 8) ? Wih : Whh;
  const u16*   X = (w < 8) ? xb  : hb;
  const int kbase = (w & 7) * 128;

  f32x4 acc[4];
  #pragma unroll
  for (int i = 0; i < 4; ++i) acc[i] = (f32x4){0.f,0.f,0.f,0.f};
  const int r16 = lane & 15;
  const int g = r16 >> 2, jq = r16 & 3;
  const float* wr = W + (size_t)(g*1024 + j0 + jq)*1024 + kbase + (lane >> 4)*8;
  #pragma unroll
  for (int t = 0; t < 4; ++t){
    float4 wa = *(const float4*)(wr + t*32);
    float4 wb = *(const float4*)(wr + t*32 + 4);
    union { bf16x8 v; uint4 u; } bf;
    bf.u.x = pk2(wa.x,wa.y); bf.u.y = pk2(wa.z,wa.w);
    bf.u.z = pk2(wb.x,wb.y); bf.u.w = pk2(wb.z,wb.w);
    #pragma unroll
    for (int fb = 0; fb < 4; ++fb){
      union { bf16x8 v; uint4 u; } af;
      af.u = *(const uint4*)(X + (size_t)(fb*16 + r16)*1024 + kbase + (lane >> 4)*8 + t*32);
      acc[fb] = __builtin_amdgcn_mfma_f32_16x16x32_bf16(af.v, bf.v, acc[fb], 0, 0, 0);
    }
  }
  #pragma unroll
  for (int fb = 0; fb < 4; ++fb)
    #pragma unroll
    for (int r = 0; r < 4; ++r) Rs[w][fb][r][lane] = acc[fb][r];
  __syncthreads();

  if (tid < 256){
    const int b  = tid >> 2, jq2 = tid & 3;
    const int j  = j0 + jq2;
    const int fb = b >> 4, q = (b >> 2) & 3, reg = b & 3;
    float gate[4];
    #pragma unroll
    for (int gg = 0; gg < 4; ++gg){
      const int li = q*16 + gg*4 + jq2;
      float a = bih[gg*1024 + j] + bhh[gg*1024 + j];
      #pragma unroll
      for (int ww = 0; ww < 16; ++ww) a += Rs[ww][fb][reg][li];
      gate[gg] = a;
    }
    float ii = sigmf(gate[0]), ff = sigmf(gate[1]);
    float gv = tanhf_fast(gate[2]), oo = sigmf(gate[3]);
    float cc = ff * c_in[(size_t)b*1024 + j] + ii * gv;
    float hh = oo * tanhf_fast(cc);
    float xo = xin[(size_t)b*1024 + j] + hh;
    xout[(size_t)b*1024 + j]  = xo;
    xoutb[(size_t)b*1024 + j] = f2bf(xo);
  }
}

// K7: mel projection — only rows with col%20 < 2 of mp_w are needed.
__global__ __launch_bounds__(256) void k_mels(
    const float* __restrict__ x2, const float* __restrict__ mp_w,
    float* __restrict__ out)
{
  const int tid = threadIdx.x, b = blockIdx.x;
  __shared__ float xL[NL];
  #pragma unroll
  for (int i = 0; i < 4; ++i){
    int j = tid + 256*i;
    xL[j] = x2[(size_t)b*NL + j];
  }
  __syncthreads();
  if (tid < 160){
    int m = tid >> 1, r = tid & 1;
    float acc = dot_rowf(mp_w + (size_t)(m*20 + r)*NL, xL, 256);
    out[b*160 + tid] = acc;
  }
}

// ---------------------------------------------------------------------------
extern "C" void kernel_launch(void* const* d_in, const int* in_sizes, int n_in,
                              void* d_out, int out_size, void* d_ws, size_t ws_size,
                              hipStream_t stream)
{
  (void)in_sizes; (void)n_in; (void)out_size; (void)ws_size;
  const float* enc     = (const float*)d_in[0];
  const float* pre_in  = (const float*)d_in[2];
  const float* h_text  = (const float*)d_in[3];
  const float* h_attn  = (const float*)d_in[5];
  const float* h_r1    = (const float*)d_in[6];
  const float* h_r2    = (const float*)d_in[7];
  const float* c_r1    = (const float*)d_in[8];
  const float* c_r2    = (const float*)d_in[9];
  const float* cv_text = (const float*)d_in[10];
  const float* cv      = (const float*)d_in[12];
  const float* fc1_w   = (const float*)d_in[13];
  const float* fc1_b   = (const float*)d_in[14];
  const float* fc2_w   = (const float*)d_in[15];
  const float* fc2_b   = (const float*)d_in[16];
  const float* tWm     = (const float*)d_in[17];
  const float* tv      = (const float*)d_in[18];
  const float* t_wih   = (const float*)d_in[21];
  const float* t_whh   = (const float*)d_in[22];
  const float* t_bih   = (const float*)d_in[23];
  const float* t_bhh   = (const float*)d_in[24];
  const float* a_wih   = (const float*)d_in[29];
  const float* a_whh   = (const float*)d_in[30];
  const float* a_bih   = (const float*)d_in[31];
  const float* a_bhh   = (const float*)d_in[32];
  const float* ri_w    = (const float*)d_in[33];
  const float* ri_b    = (const float*)d_in[34];
  const float* l1_wih  = (const float*)d_in[35];
  const float* l1_whh  = (const float*)d_in[36];
  const float* l1_bih  = (const float*)d_in[37];
  const float* l1_bhh  = (const float*)d_in[38];
  const float* l2_wih  = (const float*)d_in[39];
  const float* l2_whh  = (const float*)d_in[40];
  const float* l2_bih  = (const float*)d_in[41];
  const float* l2_bhh  = (const float*)d_in[42];
  const float* mp_w    = (const float*)d_in[43];

  // workspace layout (float units, 16B-aligned regions), ~7 MB
  float* ws    = (float*)d_ws;
  float* qp    = ws;                    // 16384
  float* attnP = qp    + 16384;         // 64*32*257 = 526336
  float* x0    = attnP + 526336;        // 65536
  float* x1    = x0    + 65536;
  float* x2    = x1    + 65536;
  float* xtext = x2    + 65536;         // 24576
  float* xattn = xtext + 24576;         // 24576
  float* htT   = xattn + 24576;         // 16384
  float* haT   = htT   + 16384;
  float* htnT  = haT   + 16384;
  float* p1T   = htnT  + 16384;         // 16384
  u16*   hb1   = (u16*)(p1T + 16384);   // 65536 u16
  u16*   hb2   = hb1 + 65536;
  u16*   xrib  = hb2 + 65536;           // 64*512
  u16*   x0b   = xrib + 32768;          // 64*1024
  u16*   x1b   = x0b + 65536;
  u16*   x2b   = x1b + 65536;           // written, unused

  k_pre1<<<144, 256, 0, stream>>>(cv_text, cv, h_text, h_attn,
      pre_in, fc1_w, fc1_b, h_r1, h_r2,
      xtext, xattn, htT, haT, p1T, hb1, hb2);
  k_pre2<<<128, 256, 0, stream>>>(p1T, fc2_w, fc2_b, xtext, xattn);
  k_gru<<<512, 512, 0, stream>>>(t_wih, t_whh, t_bih, t_bhh,
      a_wih, a_whh, a_bih, a_bhh, xtext, xattn, htT, haT, htnT, xrib);
  k_qp<<<256, 256, 0, stream>>>(tWm, htnT, qp);

  k_attn_part<<<dim3(64,32), 256, 0, stream>>>(enc, qp, tv, attnP);
  k_attn_red<<<64, 256, 0, stream>>>(attnP, xrib);

  k_mm_ri<<<64, 512, 0, stream>>>(xrib, ri_w, ri_b, x0, x0b);

  k_lstm<<<256, 1024, 0, stream>>>(l1_wih, l1_whh, x0b, hb1,
      l1_bih, l1_bhh, c_r1, x0, x1, x1b);
  k_lstm<<<256, 1024, 0, stream>>>(l2_wih, l2_whh, x1b, hb2,
      l2_bih, l2_bhh, c_r2, x1, x2, x2b);

  k_mels<<<64, 256, 0, stream>>>(x2, mp_w, (float*)d_out);
}

// Round 21
// 111.109 us; speedup vs baseline: 1.2652x; 1.0224x over previous
//
#include <hip/hip_runtime.h>
#include <hip/hip_bf16.h>

typedef unsigned short u16;
typedef unsigned int   u32;
typedef __attribute__((ext_vector_type(8))) short bf16x8;
typedef __attribute__((ext_vector_type(4))) float f32x4;

#define NB   64
#define NTX  2048
#define ND   256
#define NL   1024

#if __has_builtin(__builtin_amdgcn_exp2f)
#define EXP2F(x) __builtin_amdgcn_exp2f(x)
#else
#define EXP2F(x) exp2f(x)
#endif
#if __has_builtin(__builtin_amdgcn_rcpf)
#define RCPF(x) __builtin_amdgcn_rcpf(x)
#else
#define RCPF(x) (1.0f/(x))
#endif

__device__ __forceinline__ u16 f2bf(float f){
  union { float f; u32 u; } c; c.f = f;
  return (u16)((c.u + 0x7fffu + ((c.u >> 16) & 1u)) >> 16);
}
__device__ __forceinline__ u32 pk2(float a, float b){
  return (u32)f2bf(a) | ((u32)f2bf(b) << 16);
}
__device__ __forceinline__ float sigmf(float x){ return 1.f/(1.f+__expf(-x)); }
__device__ __forceinline__ float tanhf_fast(float x){
  x = fminf(fmaxf(x, -15.f), 15.f);
  float e = __expf(2.f*x);
  return (e - 1.f) / (e + 1.f);
}
__device__ __forceinline__ float dot_rowf(const float* __restrict__ row,
                                          const float* __restrict__ x, int K4){
  float acc = 0.f;
  for (int j = 0; j < K4; ++j){
    float4 w = *(const float4*)(row + j*4);
    const float* xp = x + j*4;
    acc += w.x*xp[0] + w.y*xp[1] + w.z*xp[2] + w.w*xp[3];
  }
  return acc;
}

// ---------------------------------------------------------------------------
// F1: blocks 0..15  : transposes [64][256] -> [256][64]
//     blocks 16..79 : fc1 batch-on-lanes -> p1T [256][64]
//     blocks 80..143: h_r1/h_r2 fp32 -> bf16 copies
// ---------------------------------------------------------------------------
__global__ __launch_bounds__(256) void k_pre1(
    const float* __restrict__ cv_text, const float* __restrict__ cv,
    const float* __restrict__ h_text,  const float* __restrict__ h_attn,
    const float* __restrict__ prenet_in,
    const float* __restrict__ fc1_w, const float* __restrict__ fc1_b,
    const float* __restrict__ h_r1, const float* __restrict__ h_r2,
    float* __restrict__ xtext, float* __restrict__ xattn,
    float* __restrict__ htT,  float* __restrict__ haT,
    float* __restrict__ p1T,
    u16* __restrict__ hb1, u16* __restrict__ hb2)
{
  __shared__ float ld[64][65];
  const int blk = blockIdx.x, tid = threadIdx.x;
  if (blk < 16){
    int a = blk >> 2; int c0 = (blk & 3)*64;
    const float* src = (a==0)?cv_text:(a==1)?cv:(a==2)?h_text:h_attn;
    float* dst = (a==0)?xtext:(a==1)?xattn:(a==2)?htT:haT;
    const int r = tid >> 2, q = tid & 3;
    #pragma unroll
    for (int i = 0; i < 4; ++i){
      float4 v = *(const float4*)(src + (size_t)r*256 + c0 + q*16 + i*4);
      ld[r][q*16+i*4+0] = v.x; ld[r][q*16+i*4+1] = v.y;
      ld[r][q*16+i*4+2] = v.z; ld[r][q*16+i*4+3] = v.w;
    }
    __syncthreads();
    const int cc = tid >> 2;
    #pragma unroll
    for (int i = 0; i < 4; ++i){
      int b0 = q*16 + i*4;
      float4 o = { ld[b0+0][cc], ld[b0+1][cc], ld[b0+2][cc], ld[b0+3][cc] };
      *(float4*)(dst + (size_t)(c0+cc)*64 + b0) = o;
    }
  } else if (blk < 80){
    const int wave = tid >> 6, lane = tid & 63;
    const int n = (blk - 16)*4 + wave;
    float acc = fc1_b[n];
    const float* wr = fc1_w + (size_t)n*80;
    const float* xr = prenet_in + (size_t)lane*80;
    #pragma unroll
    for (int k = 0; k < 80; k += 4){
      float4 w = *(const float4*)(wr + k);
      acc += w.x*xr[k] + w.y*xr[k+1] + w.z*xr[k+2] + w.w*xr[k+3];
    }
    p1T[n*64 + lane] = fmaxf(acc, 0.f);
  } else {
    const int t2 = blk - 80;
    const float* src = (t2 < 32) ? h_r1 : h_r2;
    u16* dst = (t2 < 32) ? hb1 : hb2;
    const int base = (t2 & 31)*2048 + tid*8;
    float4 a = *(const float4*)(src + base);
    float4 b = *(const float4*)(src + base + 4);
    uint4 o = { pk2(a.x,a.y), pk2(a.z,a.w), pk2(b.x,b.y), pk2(b.z,b.w) };
    *(uint4*)(dst + base) = o;
  }
}

// F2: fc2, 128 blocks (block = n), 4-wave k-split + LDS reduce.
__global__ __launch_bounds__(256) void k_pre2(
    const float* __restrict__ p1T,
    const float* __restrict__ fc2_w, const float* __restrict__ fc2_b,
    float* __restrict__ xtext, float* __restrict__ xattn)
{
  const int tid = threadIdx.x, w = tid >> 6, lane = tid & 63;
  const int n = blockIdx.x;
  __shared__ float red[4][64];
  float acc = 0.f;
  const float* wr = fc2_w + (size_t)n*256 + w*64;
  const float* xb = p1T + w*64*64 + lane;
  #pragma unroll
  for (int k = 0; k < 64; k += 4){
    float4 wv = *(const float4*)(wr + k);
    acc += wv.x*xb[(k+0)*64] + wv.y*xb[(k+1)*64]
         + wv.z*xb[(k+2)*64] + wv.w*xb[(k+3)*64];
  }
  red[w][lane] = acc;
  __syncthreads();
  if (w == 0){
    float v = fmaxf(red[0][lane]+red[1][lane]+red[2][lane]+red[3][lane] + fc2_b[n], 0.f);
    xtext[(size_t)(256+n)*64 + lane] = v;
    xattn[(size_t)(256+n)*64 + lane] = v;
  }
}

// F3: GRUs. 512 blocks x 512 threads (8 waves k-split + LDS reduce).
__global__ __launch_bounds__(512) void k_gru(
    const float* __restrict__ t_wih, const float* __restrict__ t_whh,
    const float* __restrict__ t_bih, const float* __restrict__ t_bhh,
    const float* __restrict__ a_wih, const float* __restrict__ a_whh,
    const float* __restrict__ a_bih, const float* __restrict__ a_bhh,
    const float* __restrict__ xtext, const float* __restrict__ xattn,
    const float* __restrict__ htT,  const float* __restrict__ haT,
    float* __restrict__ htnT, u16* __restrict__ xrib)
{
  const int tid = threadIdx.x, w = tid >> 6, lane = tid & 63;
  const int isA = blockIdx.x >= 256;
  const int d = blockIdx.x & 255;
  const float* wih = isA ? a_wih : t_wih;
  const float* whh = isA ? a_whh : t_whh;
  const float* xT  = isA ? xattn : xtext;
  const float* hT  = isA ? haT   : htT;
  __shared__ float red[8][6][64];
  float s0=0.f,s1=0.f,s2=0.f,s3=0.f,s4=0.f,s5=0.f;
  {
    const float* wr = wih + (size_t)d*384       + w*48;
    const float* wz = wih + (size_t)(256+d)*384 + w*48;
    const float* wn = wih + (size_t)(512+d)*384 + w*48;
    const float* xb = xT + w*48*64 + lane;
    #pragma unroll 4
    for (int k = 0; k < 48; k += 4){
      float4 ar = *(const float4*)(wr + k);
      float4 az = *(const float4*)(wz + k);
      float4 an = *(const float4*)(wn + k);
      float x0 = xb[(k+0)*64], x1 = xb[(k+1)*64];
      float x2 = xb[(k+2)*64], x3 = xb[(k+3)*64];
      s0 += ar.x*x0 + ar.y*x1 + ar.z*x2 + ar.w*x3;
      s1 += az.x*x0 + az.y*x1 + az.z*x2 + az.w*x3;
      s2 += an.x*x0 + an.y*x1 + an.z*x2 + an.w*x3;
    }
  }
  {
    const float* vr = whh + (size_t)d*256       + w*32;
    const float* vz = whh + (size_t)(256+d)*256 + w*32;
    const float* vn = whh + (size_t)(512+d)*256 + w*32;
    const float* hb = hT + w*32*64 + lane;
    #pragma unroll 4
    for (int k = 0; k < 32; k += 4){
      float4 ar = *(const float4*)(vr + k);
      float4 az = *(const float4*)(vz + k);
      float4 an = *(const float4*)(vn + k);
      float h0 = hb[(k+0)*64], h1 = hb[(k+1)*64];
      float h2 = hb[(k+2)*64], h3 = hb[(k+3)*64];
      s3 += ar.x*h0 + ar.y*h1 + ar.z*h2 + ar.w*h3;
      s4 += az.x*h0 + az.y*h1 + az.z*h2 + az.w*h3;
      s5 += an.x*h0 + an.y*h1 + an.z*h2 + an.w*h3;
    }
  }
  red[w][0][lane]=s0; red[w][1][lane]=s1; red[w][2][lane]=s2;
  red[w][3][lane]=s3; red[w][4][lane]=s4; red[w][5][lane]=s5;
  __syncthreads();
  if (w == 0){
    const float* bih = isA ? a_bih : t_bih;
    const float* bhh = isA ? a_bhh : t_bhh;
    float g6[6];
    #pragma unroll
    for (int i = 0; i < 6; ++i){
      float a = 0.f;
      #pragma unroll
      for (int ww = 0; ww < 8; ++ww) a += red[ww][i][lane];
      g6[i] = a;
    }
    float gir = bih[d]     + g6[0];
    float giz = bih[256+d] + g6[1];
    float gin = bih[512+d] + g6[2];
    float ghr = bhh[d]     + g6[3];
    float ghz = bhh[256+d] + g6[4];
    float ghn = bhh[512+d] + g6[5];
    float hd = hT[d*64 + lane];
    float r  = sigmf(gir + ghr), z = sigmf(giz + ghz);
    float nn = tanhf_fast(gin + r*ghn);
    float hnew = (1.f - z)*nn + z*hd;
    if (isA) xrib[(size_t)lane*512 + 256 + d] = f2bf(hnew);
    else     htnT[(size_t)d*64 + lane]        = hnew;
  }
}

// F4: qp. 256 blocks (block = d), 4-wave k-split + reduce.
__global__ __launch_bounds__(256) void k_qp(
    const float* __restrict__ tWm, const float* __restrict__ htnT,
    float* __restrict__ qp)
{
  const int tid = threadIdx.x, w = tid >> 6, lane = tid & 63;
  const int d = blockIdx.x;
  __shared__ float red[4][64];
  float acc = 0.f;
  const float* wr = tWm + (size_t)d*256 + w*64;
  const float* xb = htnT + w*64*64 + lane;
  #pragma unroll
  for (int k = 0; k < 64; k += 4){
    float4 wv = *(const float4*)(wr + k);
    acc += wv.x*xb[(k+0)*64] + wv.y*xb[(k+1)*64]
         + wv.z*xb[(k+2)*64] + wv.w*xb[(k+3)*64];
  }
  red[w][lane] = acc;
  __syncthreads();
  if (w == 0)
    qp[lane*ND + d] = red[0][lane]+red[1][lane]+red[2][lane]+red[3][lane];
}

// ---------------------------------------------------------------------------
// K2: attention partial pass, batch-load / flat-reduce form (champion).
// Grid (64 b, 32 chunks of 64 t), 256 thr. Wave owns 16 rows.
// ---------------------------------------------------------------------------
__global__ __launch_bounds__(256) void k_attn_part(
    const float* __restrict__ enc, const float* __restrict__ qp,
    const float* __restrict__ tv,  float* __restrict__ attnP)
{
  const int tid = threadIdx.x, b = blockIdx.x, ch = blockIdx.y;
  const int w = tid >> 6, lane = tid & 63;
  const float C2  = 2.885390082f;      // 2*log2(e)
  const float L2E = 1.4426950408f;     // log2(e)
  __shared__ float qpL[256], vL[256];
  __shared__ float part[4][16][65];
  __shared__ float wbc[4][16];
  __shared__ float ctxL[4][256], sL[4];
  qpL[tid] = qp[b*ND + tid] * C2;
  vL[tid]  = tv[tid] * 2.f;
  __syncthreads();

  const float q0 = qpL[lane*4+0], q1 = qpL[lane*4+1], q2 = qpL[lane*4+2], q3 = qpL[lane*4+3];
  const float v0 = vL[lane*4+0],  v1 = vL[lane*4+1],  v2 = vL[lane*4+2],  v3 = vL[lane*4+3];
  float vs = 0.5f*(v0 + v1 + v2 + v3);
  #pragma unroll
  for (int off = 1; off < 64; off <<= 1) vs += __shfl_xor(vs, off);
  const float VS = vs;

  // S1: batch-load 16 rows (independent, all issued before first use)
  const float* base = enc + ((size_t)b*NTX + (size_t)ch*64 + w*16)*ND + lane*4;
  float4 ev[16];
  #pragma unroll
  for (int i = 0; i < 16; ++i) ev[i] = *(const float4*)(base + (size_t)i*ND);

  // S2: per-lane partial scores (pure VALU)
  #pragma unroll
  for (int i = 0; i < 16; ++i){
    float u0 = EXP2F(__builtin_fmaf(ev[i].x, C2, q0));
    float u1 = EXP2F(__builtin_fmaf(ev[i].y, C2, q1));
    float u2 = EXP2F(__builtin_fmaf(ev[i].z, C2, q2));
    float u3 = EXP2F(__builtin_fmaf(ev[i].w, C2, q3));
    part[w][i][lane] = v0*RCPF(u0 + 1.f) + v1*RCPF(u1 + 1.f)
                     + v2*RCPF(u2 + 1.f) + v3*RCPF(u3 + 1.f);
  }
  __syncthreads();

  // S3: reduce each row: lane -> (row rr, quarter q4); 16 adds + 2 shfl
  {
    const int rr = lane >> 2, q4 = lane & 3;
    float s = 0.f;
    #pragma unroll
    for (int i = 0; i < 16; ++i) s += part[w][rr][q4*16 + i];
    s += __shfl_xor(s, 1);
    s += __shfl_xor(s, 2);
    if (q4 == 0) wbc[w][rr] = EXP2F((VS - s) * L2E);
  }
  __syncthreads();

  // S4: weighted context from in-register rows
  float cx0=0.f, cx1=0.f, cx2=0.f, cx3=0.f, sacc=0.f;
  #pragma unroll
  for (int r = 0; r < 16; ++r){
    float wv = wbc[w][r];
    sacc += wv;
    cx0 = __builtin_fmaf(wv, ev[r].x, cx0);
    cx1 = __builtin_fmaf(wv, ev[r].y, cx1);
    cx2 = __builtin_fmaf(wv, ev[r].z, cx2);
    cx3 = __builtin_fmaf(wv, ev[r].w, cx3);
  }
  ctxL[w][lane*4+0]=cx0; ctxL[w][lane*4+1]=cx1;
  ctxL[w][lane*4+2]=cx2; ctxL[w][lane*4+3]=cx3;
  if (lane == 0) sL[w] = sacc;
  __syncthreads();
  float c = ctxL[0][tid]+ctxL[1][tid]+ctxL[2][tid]+ctxL[3][tid];
  float* dst = attnP + ((size_t)b*32 + ch)*257;
  dst[tid] = c;
  if (tid == 0) dst[256] = sL[0]+sL[1]+sL[2]+sL[3];
}

// K3: combine 32 chunk partials -> xrib rows 0..255 (bf16)
__global__ __launch_bounds__(256) void k_attn_red(
    const float* __restrict__ attnP, u16* __restrict__ xrib)
{
  const int tid = threadIdx.x, b = blockIdx.x;
  float c = 0.f, s = 0.f;
  for (int ch = 0; ch < 32; ++ch){
    const float* src = attnP + ((size_t)b*32 + ch)*257;
    c += src[tid]; s += src[256];
  }
  xrib[(size_t)b*512 + tid] = f2bf(c / s);
}

// ---------------------------------------------------------------------------
// MFMA GEMMs (A direct from global bf16, no LDS staging).
// D[b][col]: b = fb*16+(lane>>4)*4+reg, col = lane&15.
// ---------------------------------------------------------------------------

// ri projection: 64 blocks x 512 threads; 8 waves k-split (64 each).
__global__ __launch_bounds__(512) void k_mm_ri(
    const u16* __restrict__ xrib, const float* __restrict__ ri_w,
    const float* __restrict__ ri_b, float* __restrict__ x0,
    u16* __restrict__ x0b)
{
  __shared__ float Rs[8][4][4][65];
  const int tid = threadIdx.x, lane = tid & 63, w = tid >> 6;
  const int n0 = blockIdx.x * 16;
  f32x4 acc[4];
  #pragma unroll
  for (int i = 0; i < 4; ++i) acc[i] = (f32x4){0.f,0.f,0.f,0.f};
  const int kbase = w*64;
  const float* wr = ri_w + (size_t)(n0 + (lane & 15))*512 + kbase + (lane >> 4)*8;
  const u16* xs = xrib + (size_t)(lane & 15)*512 + kbase + (lane >> 4)*8;
  #pragma unroll
  for (int t = 0; t < 2; ++t){
    float4 wa = *(const float4*)(wr + t*32);
    float4 wb = *(const float4*)(wr + t*32 + 4);
    union { bf16x8 v; uint4 u; } bf;
    bf.u.x = pk2(wa.x,wa.y); bf.u.y = pk2(wa.z,wa.w);
    bf.u.z = pk2(wb.x,wb.y); bf.u.w = pk2(wb.z,wb.w);
    #pragma unroll
    for (int fb = 0; fb < 4; ++fb){
      union { bf16x8 v; uint4 u; } af;
      af.u = *(const uint4*)(xs + fb*16*512 + t*32);
      acc[fb] = __builtin_amdgcn_mfma_f32_16x16x32_bf16(af.v, bf.v, acc[fb], 0, 0, 0);
    }
  }
  #pragma unroll
  for (int fb = 0; fb < 4; ++fb)
    #pragma unroll
    for (int r = 0; r < 4; ++r) Rs[w][fb][r][lane] = acc[fb][r];
  __syncthreads();
  if (tid < 256){
    const int b = tid >> 2, c4 = (tid & 3)*4;
    const int fb = b >> 4, q = (b >> 2) & 3, reg = b & 3;
    #pragma unroll
    for (int cc = 0; cc < 4; ++cc){
      const int c = c4 + cc;
      float v = ri_b[n0 + c];
      #pragma unroll
      for (int ww = 0; ww < 8; ++ww) v += Rs[ww][fb][reg][q*16 + c];
      x0[(size_t)b*1024 + n0 + c]  = v;
      x0b[(size_t)b*1024 + n0 + c] = f2bf(v);
    }
  }
}

// ---------------------------------------------------------------------------
// Fused LSTM layer: 256 blocks x 1024 threads (16 waves). Block = 4 j-cols;
// 16 MFMA rows = 4 gates x 4 j. Waves 0..7: ih K-chunks of 128; 8..15: hh.
// LDS reduce, then same block applies cell + residual.
// ---------------------------------------------------------------------------
__global__ __launch_bounds__(1024) void k_lstm(
    const float* __restrict__ Wih, const float* __restrict__ Whh,
    const u16* __restrict__ xb, const u16* __restrict__ hb,
    const float* __restrict__ bih, const float* __restrict__ bhh,
    const float* __restrict__ c_in,
    const float* __restrict__ xin, float* __restrict__ xout,
    u16* __restrict__ xoutb)
{
  __shared__ float Rs[16][4][4][65];
  const int tid = threadIdx.x, lane = tid & 63, w = tid >> 6;
  const int j0 = blockIdx.x * 4;
  const float* W = (w < 8) ? Wih : Whh;
  const u16*   X = (w < 8) ? xb  : hb;
  const int kbase = (w & 7) * 128;

  f32x4 acc[4];
  #pragma unroll
  for (int i = 0; i < 4; ++i) acc[i] = (f32x4){0.f,0.f,0.f,0.f};
  const int r16 = lane & 15;
  const int g = r16 >> 2, jq = r16 & 3;
  const float* wr = W + (size_t)(g*1024 + j0 + jq)*1024 + kbase + (lane >> 4)*8;
  #pragma unroll
  for (int t = 0; t < 4; ++t){
    float4 wa = *(const float4*)(wr + t*32);
    float4 wb = *(const float4*)(wr + t*32 + 4);
    union { bf16x8 v; uint4 u; } bf;
    bf.u.x = pk2(wa.x,wa.y); bf.u.y = pk2(wa.z,wa.w);
    bf.u.z = pk2(wb.x,wb.y); bf.u.w = pk2(wb.z,wb.w);
    #pragma unroll
    for (int fb = 0; fb < 4; ++fb){
      union { bf16x8 v; uint4 u; } af;
      af.u = *(const uint4*)(X + (size_t)(fb*16 + r16)*1024 + kbase + (lane >> 4)*8 + t*32);
      acc[fb] = __builtin_amdgcn_mfma_f32_16x16x32_bf16(af.v, bf.v, acc[fb], 0, 0, 0);
    }
  }
  #pragma unroll
  for (int fb = 0; fb < 4; ++fb)
    #pragma unroll
    for (int r = 0; r < 4; ++r) Rs[w][fb][r][lane] = acc[fb][r];
  __syncthreads();

  if (tid < 256){
    const int b  = tid >> 2, jq2 = tid & 3;
    const int j  = j0 + jq2;
    const int fb = b >> 4, q = (b >> 2) & 3, reg = b & 3;
    float gate[4];
    #pragma unroll
    for (int gg = 0; gg < 4; ++gg){
      const int li = q*16 + gg*4 + jq2;
      float a = bih[gg*1024 + j] + bhh[gg*1024 + j];
      #pragma unroll
      for (int ww = 0; ww < 16; ++ww) a += Rs[ww][fb][reg][li];
      gate[gg] = a;
    }
    float ii = sigmf(gate[0]), ff = sigmf(gate[1]);
    float gv = tanhf_fast(gate[2]), oo = sigmf(gate[3]);
    float cc = ff * c_in[(size_t)b*1024 + j] + ii * gv;
    float hh = oo * tanhf_fast(cc);
    float xo = xin[(size_t)b*1024 + j] + hh;
    xout[(size_t)b*1024 + j]  = xo;
    xoutb[(size_t)b*1024 + j] = f2bf(xo);
  }
}

// K7: mel projection — only rows with col%20 < 2 of mp_w are needed.
__global__ __launch_bounds__(256) void k_mels(
    const float* __restrict__ x2, const float* __restrict__ mp_w,
    float* __restrict__ out)
{
  const int tid = threadIdx.x, b = blockIdx.x;
  __shared__ float xL[NL];
  #pragma unroll
  for (int i = 0; i < 4; ++i){
    int j = tid + 256*i;
    xL[j] = x2[(size_t)b*NL + j];
  }
  __syncthreads();
  if (tid < 160){
    int m = tid >> 1, r = tid & 1;
    float acc = dot_rowf(mp_w + (size_t)(m*20 + r)*NL, xL, 256);
    out[b*160 + tid] = acc;
  }
}

// ---------------------------------------------------------------------------
extern "C" void kernel_launch(void* const* d_in, const int* in_sizes, int n_in,
                              void* d_out, int out_size, void* d_ws, size_t ws_size,
                              hipStream_t stream)
{
  (void)in_sizes; (void)n_in; (void)out_size; (void)ws_size;
  const float* enc     = (const float*)d_in[0];
  const float* pre_in  = (const float*)d_in[2];
  const float* h_text  = (const float*)d_in[3];
  const float* h_attn  = (const float*)d_in[5];
  const float* h_r1    = (const float*)d_in[6];
  const float* h_r2    = (const float*)d_in[7];
  const float* c_r1    = (const float*)d_in[8];
  const float* c_r2    = (const float*)d_in[9];
  const float* cv_text = (const float*)d_in[10];
  const float* cv      = (const float*)d_in[12];
  const float* fc1_w   = (const float*)d_in[13];
  const float* fc1_b   = (const float*)d_in[14];
  const float* fc2_w   = (const float*)d_in[15];
  const float* fc2_b   = (const float*)d_in[16];
  const float* tWm     = (const float*)d_in[17];
  const float* tv      = (const float*)d_in[18];
  const float* t_wih   = (const float*)d_in[21];
  const float* t_whh   = (const float*)d_in[22];
  const float* t_bih   = (const float*)d_in[23];
  const float* t_bhh   = (const float*)d_in[24];
  const float* a_wih   = (const float*)d_in[29];
  const float* a_whh   = (const float*)d_in[30];
  const float* a_bih   = (const float*)d_in[31];
  const float* a_bhh   = (const float*)d_in[32];
  const float* ri_w    = (const float*)d_in[33];
  const float* ri_b    = (const float*)d_in[34];
  const float* l1_wih  = (const float*)d_in[35];
  const float* l1_whh  = (const float*)d_in[36];
  const float* l1_bih  = (const float*)d_in[37];
  const float* l1_bhh  = (const float*)d_in[38];
  const float* l2_wih  = (const float*)d_in[39];
  const float* l2_whh  = (const float*)d_in[40];
  const float* l2_bih  = (const float*)d_in[41];
  const float* l2_bhh  = (const float*)d_in[42];
  const float* mp_w    = (const float*)d_in[43];

  // workspace layout (float units, 16B-aligned regions), ~7 MB
  float* ws    = (float*)d_ws;
  float* qp    = ws;                    // 16384
  float* attnP = qp    + 16384;         // 64*32*257 = 526336
  float* x0    = attnP + 526336;        // 65536
  float* x1    = x0    + 65536;
  float* x2    = x1    + 65536;
  float* xtext = x2    + 65536;         // 24576
  float* xattn = xtext + 24576;         // 24576
  float* htT   = xattn + 24576;         // 16384
  float* haT   = htT   + 16384;
  float* htnT  = haT   + 16384;
  float* p1T   = htnT  + 16384;         // 16384
  u16*   hb1   = (u16*)(p1T + 16384);   // 65536 u16
  u16*   hb2   = hb1 + 65536;
  u16*   xrib  = hb2 + 65536;           // 64*512
  u16*   x0b   = xrib + 32768;          // 64*1024
  u16*   x1b   = x0b + 65536;
  u16*   x2b   = x1b + 65536;           // written, unused

  k_pre1<<<144, 256, 0, stream>>>(cv_text, cv, h_text, h_attn,
      pre_in, fc1_w, fc1_b, h_r1, h_r2,
      xtext, xattn, htT, haT, p1T, hb1, hb2);
  k_pre2<<<128, 256, 0, stream>>>(p1T, fc2_w, fc2_b, xtext, xattn);
  k_gru<<<512, 512, 0, stream>>>(t_wih, t_whh, t_bih, t_bhh,
      a_wih, a_whh, a_bih, a_bhh, xtext, xattn, htT, haT, htnT, xrib);
  k_qp<<<256, 256, 0, stream>>>(tWm, htnT, qp);

  k_attn_part<<<dim3(64,32), 256, 0, stream>>>(enc, qp, tv, attnP);
  k_attn_red<<<64, 256, 0, stream>>>(attnP, xrib);

  k_mm_ri<<<64, 512, 0, stream>>>(xrib, ri_w, ri_b, x0, x0b);

  k_lstm<<<256, 1024, 0, stream>>>(l1_wih, l1_whh, x0b, hb1,
      l1_bih, l1_bhh, c_r1, x0, x1, x1b);
  k_lstm<<<256, 1024, 0, stream>>>(l2_wih, l2_whh, x1b, hb2,
      l2_bih, l2_bhh, c_r2, x1, x2, x2b);

  k_mels<<<64, 256, 0, stream>>>(x2, mp_w, (float*)d_out);
}